// Round 5
// baseline (573.809 us; speedup 1.0000x reference)
//
#include <hip/hip_runtime.h>
#include <hip/hip_bf16.h>

// BCE: mean over 67.1M elements of -(target ? log(p) : log(1-p)).
// R5 = RESUBMIT of R4's MEASUREMENT PROBE (R4 hit GPUAcquisitionTimeout).
// Output path is bit-identical to R3 (pass 1). A second discarded sweep
// (pass 2, kept alive via asm-volatile sinks) doubles the dispatch
// duration so bce_partial_kernel enters rocprof's top-5 and we see its
// FETCH_SIZE / hbm_gbps / VALUBusy / OccupancyPercent. Decision:
// >=6 TB/s -> kernel at BW floor, revert & declare roofline;
// ~3.5-4 TB/s -> real headroom, counters say where.

#define BLOCKS 2048
#define THREADS 256

typedef float  f32x4 __attribute__((ext_vector_type(4)));
typedef int    i32x4 __attribute__((ext_vector_type(4)));

__device__ __forceinline__ float bce4(f32x4 pv, i32x4 tv) {
  float s = 0.0f;
  s += __logf(tv.x ? pv.x : 1.0f - pv.x);
  s += __logf(tv.y ? pv.y : 1.0f - pv.y);
  s += __logf(tv.z ? pv.z : 1.0f - pv.z);
  s += __logf(tv.w ? pv.w : 1.0f - pv.w);
  return s;
}

__global__ __launch_bounds__(THREADS) void bce_partial_kernel(
    const float* __restrict__ p, const int* __restrict__ t,
    double* __restrict__ partial, long long nvec, long long n) {
  long long tid = (long long)blockIdx.x * blockDim.x + threadIdx.x;
  long long stride = (long long)gridDim.x * blockDim.x;

  const f32x4* p4 = reinterpret_cast<const f32x4*>(p);
  const i32x4* t4 = reinterpret_cast<const i32x4*>(t);

  // ---- pass 1: the real computation (identical to R3) ----
  float s0 = 0.0f, s1 = 0.0f, s2 = 0.0f, s3 = 0.0f;
  long long i = tid;
  for (; i + 3 * stride < nvec; i += 4 * stride) {
    f32x4 pa = __builtin_nontemporal_load(&p4[i]);
    f32x4 pb = __builtin_nontemporal_load(&p4[i + stride]);
    f32x4 pc = __builtin_nontemporal_load(&p4[i + 2 * stride]);
    f32x4 pd = __builtin_nontemporal_load(&p4[i + 3 * stride]);
    i32x4 ta = __builtin_nontemporal_load(&t4[i]);
    i32x4 tb = __builtin_nontemporal_load(&t4[i + stride]);
    i32x4 tc = __builtin_nontemporal_load(&t4[i + 2 * stride]);
    i32x4 td = __builtin_nontemporal_load(&t4[i + 3 * stride]);
    s0 += bce4(pa, ta);
    s1 += bce4(pb, tb);
    s2 += bce4(pc, tc);
    s3 += bce4(pd, td);
  }
  for (; i < nvec; i += stride) {
    f32x4 pa = __builtin_nontemporal_load(&p4[i]);
    i32x4 ta = __builtin_nontemporal_load(&t4[i]);
    s0 += bce4(pa, ta);
  }
  float sum = (s0 + s1) + (s2 + s3);

  long long tail_start = nvec * 4;
  long long tail_n = n - tail_start;
  if (tid < tail_n) {
    long long j = tail_start + tid;
    sum += __logf(t[j] ? p[j] : 1.0f - p[j]);
  }

  // ---- pass 2: BW probe. Same sweep, separate accumulators, result
  // discarded but kept live (no DCE) via asm sinks. Runs AFTER pass 1 so
  // pass 1 sees production cache state. ----
  float u0 = 0.0f, u1 = 0.0f, u2 = 0.0f, u3 = 0.0f;
  long long j2 = tid;
  for (; j2 + 3 * stride < nvec; j2 += 4 * stride) {
    f32x4 pa = __builtin_nontemporal_load(&p4[j2]);
    f32x4 pb = __builtin_nontemporal_load(&p4[j2 + stride]);
    f32x4 pc = __builtin_nontemporal_load(&p4[j2 + 2 * stride]);
    f32x4 pd = __builtin_nontemporal_load(&p4[j2 + 3 * stride]);
    i32x4 ta = __builtin_nontemporal_load(&t4[j2]);
    i32x4 tb = __builtin_nontemporal_load(&t4[j2 + stride]);
    i32x4 tc = __builtin_nontemporal_load(&t4[j2 + 2 * stride]);
    i32x4 td = __builtin_nontemporal_load(&t4[j2 + 3 * stride]);
    u0 += bce4(pa, ta);
    u1 += bce4(pb, tb);
    u2 += bce4(pc, tc);
    u3 += bce4(pd, td);
  }
  asm volatile("" :: "v"(u0), "v"(u1), "v"(u2), "v"(u3));

  // ---- reduce pass 1 only ----
  for (int off = 32; off > 0; off >>= 1) sum += __shfl_down(sum, off);

  __shared__ float wsum[THREADS / 64];
  int lane = threadIdx.x & 63;
  int wave = threadIdx.x >> 6;
  if (lane == 0) wsum[wave] = sum;
  __syncthreads();
  if (threadIdx.x == 0) {
    double bsum = 0.0;
    #pragma unroll
    for (int w = 0; w < THREADS / 64; ++w) bsum += (double)wsum[w];
    partial[blockIdx.x] = bsum;  // every slot written every launch
  }
}

__global__ __launch_bounds__(256) void bce_final_kernel(
    const double* __restrict__ partial, int nparts, float* __restrict__ out,
    double inv_n) {
  double s = 0.0;
  for (int i = threadIdx.x; i < nparts; i += blockDim.x) s += partial[i];
  for (int off = 32; off > 0; off >>= 1) s += __shfl_down(s, off);
  __shared__ double wsum[4];
  int lane = threadIdx.x & 63;
  int wave = threadIdx.x >> 6;
  if (lane == 0) wsum[wave] = s;
  __syncthreads();
  if (threadIdx.x == 0) {
    double tot = wsum[0] + wsum[1] + wsum[2] + wsum[3];
    out[0] = (float)(-tot * inv_n);
  }
}

extern "C" void kernel_launch(void* const* d_in, const int* in_sizes, int n_in,
                              void* d_out, int out_size, void* d_ws, size_t ws_size,
                              hipStream_t stream) {
  const float* p = (const float*)d_in[0];
  const int* t = (const int*)d_in[1];
  float* out = (float*)d_out;
  double* partial = (double*)d_ws;

  long long n = (long long)in_sizes[0];
  long long nvec = n / 4;

  long long want = (nvec + THREADS - 1) / THREADS;
  int blocks = (int)(want < BLOCKS ? (want > 0 ? want : 1) : BLOCKS);

  bce_partial_kernel<<<blocks, THREADS, 0, stream>>>(p, t, partial, nvec, n);
  bce_final_kernel<<<1, 256, 0, stream>>>(partial, blocks, out, 1.0 / (double)n);
}

// Round 6
// 498.425 us; speedup vs baseline: 1.1512x; 1.1512x over previous
//
#include <hip/hip_runtime.h>
#include <hip/hip_bf16.h>

// BCE: mean over 67.1M elements of -(target ? log(p) : log(1-p)).
// R6: VALU-diet + static-schedule kernel.
//  - R5 probe showed: kernel ~128us @ 4.2 TB/s (floor 85us), VGPR=36 (no
//    loads kept in flight), VALU work serializes with memory ~1:1.
//  - Fix: compile-time trip counts (n is fixed), 32-bit shared p/t byte
//    offsets against SGPR bases, hardware log2 (v_log_f32, 1 TRANS) with
//    deferred *ln2 in the double final reduce, launch_bounds(256,1) +
//    unroll so the compiler can hold ~16 dwordx4 loads in flight.

#define BLOCKS 2048
#define THREADS 256
#define NELEM 67108864LL        // 16384*4096 (harness shape)
#define NVEC 16777216LL         // NELEM/4
#define STRIDE_VEC 524288       // BLOCKS*THREADS vec4s per sweep step
#define OUTER 8                 // NVEC / (4*STRIDE_VEC), exact

typedef float  f32x4 __attribute__((ext_vector_type(4)));
typedef int    i32x4 __attribute__((ext_vector_type(4)));

__device__ __forceinline__ float lg2(float x) {
#if __has_builtin(__builtin_amdgcn_logf)
  return __builtin_amdgcn_logf(x);   // v_log_f32: hardware log2
#else
  return __log2f(x);
#endif
}

// sum of log2(target ? p : 1-p) over a vec4
__device__ __forceinline__ float bce4_lg2(f32x4 pv, i32x4 tv) {
  float a0 = tv.x ? pv.x : 1.0f - pv.x;
  float a1 = tv.y ? pv.y : 1.0f - pv.y;
  float a2 = tv.z ? pv.z : 1.0f - pv.z;
  float a3 = tv.w ? pv.w : 1.0f - pv.w;
  return (lg2(a0) + lg2(a1)) + (lg2(a2) + lg2(a3));
}

__device__ __forceinline__ void block_reduce_store(
    float sum, double* __restrict__ partial) {
  for (int off = 32; off > 0; off >>= 1) sum += __shfl_down(sum, off);
  __shared__ float wsum[THREADS / 64];
  int lane = threadIdx.x & 63;
  int wave = threadIdx.x >> 6;
  if (lane == 0) wsum[wave] = sum;
  __syncthreads();
  if (threadIdx.x == 0) {
    double bsum = 0.0;
    #pragma unroll
    for (int w = 0; w < THREADS / 64; ++w) bsum += (double)wsum[w];
    partial[blockIdx.x] = bsum;  // every slot written every launch
  }
}

// Fast path: n == NELEM exactly. Fully static trip counts, no tails.
__global__ __launch_bounds__(THREADS, 1) void bce_fast_kernel(
    const float* __restrict__ p, const int* __restrict__ t,
    double* __restrict__ partial) {
  const char* pb = (const char*)p;
  const char* tb = (const char*)t;
  // one 32-bit byte offset serves both p and t (both 16 B per vec4)
  unsigned off = ((unsigned)(blockIdx.x * THREADS + threadIdx.x)) * 16u;
  const unsigned SS = (unsigned)STRIDE_VEC * 16u;   // 8 MB stream spacing
  float s0 = 0.0f, s1 = 0.0f, s2 = 0.0f, s3 = 0.0f;
  #pragma unroll 2
  for (int o = 0; o < OUTER; ++o) {
    f32x4 pa = __builtin_nontemporal_load((const f32x4*)(pb + off));
    f32x4 pb_ = __builtin_nontemporal_load((const f32x4*)(pb + off + SS));
    f32x4 pc = __builtin_nontemporal_load((const f32x4*)(pb + off + 2 * SS));
    f32x4 pd = __builtin_nontemporal_load((const f32x4*)(pb + off + 3 * SS));
    i32x4 ta = __builtin_nontemporal_load((const i32x4*)(tb + off));
    i32x4 tb_ = __builtin_nontemporal_load((const i32x4*)(tb + off + SS));
    i32x4 tc = __builtin_nontemporal_load((const i32x4*)(tb + off + 2 * SS));
    i32x4 td = __builtin_nontemporal_load((const i32x4*)(tb + off + 3 * SS));
    s0 += bce4_lg2(pa, ta);
    s1 += bce4_lg2(pb_, tb_);
    s2 += bce4_lg2(pc, tc);
    s3 += bce4_lg2(pd, td);
    off += 4u * SS;  // 32 MB per outer iter; max < 2^28, fits 32-bit
  }
  block_reduce_store((s0 + s1) + (s2 + s3), partial);
}

// Generic fallback for any n (grid-stride, runtime bounds).
__global__ __launch_bounds__(THREADS) void bce_generic_kernel(
    const float* __restrict__ p, const int* __restrict__ t,
    double* __restrict__ partial, long long nvec, long long n) {
  long long tid = (long long)blockIdx.x * blockDim.x + threadIdx.x;
  long long stride = (long long)gridDim.x * blockDim.x;
  const f32x4* p4 = reinterpret_cast<const f32x4*>(p);
  const i32x4* t4 = reinterpret_cast<const i32x4*>(t);
  float sum = 0.0f;
  for (long long i = tid; i < nvec; i += stride)
    sum += bce4_lg2(p4[i], t4[i]);
  long long tail_start = nvec * 4;
  if (tid < n - tail_start) {
    long long j = tail_start + tid;
    sum += lg2(t[j] ? p[j] : 1.0f - p[j]);
  }
  block_reduce_store(sum, partial);
}

__global__ __launch_bounds__(256) void bce_final_kernel(
    const double* __restrict__ partial, int nparts, float* __restrict__ out,
    double scale) {  // scale = ln2 / n; partials are log2-sums
  double s = 0.0;
  for (int i = threadIdx.x; i < nparts; i += blockDim.x) s += partial[i];
  for (int off = 32; off > 0; off >>= 1) s += __shfl_down(s, off);
  __shared__ double wsum[4];
  int lane = threadIdx.x & 63;
  int wave = threadIdx.x >> 6;
  if (lane == 0) wsum[wave] = s;
  __syncthreads();
  if (threadIdx.x == 0) {
    double tot = wsum[0] + wsum[1] + wsum[2] + wsum[3];
    out[0] = (float)(-tot * scale);
  }
}

extern "C" void kernel_launch(void* const* d_in, const int* in_sizes, int n_in,
                              void* d_out, int out_size, void* d_ws, size_t ws_size,
                              hipStream_t stream) {
  const float* p = (const float*)d_in[0];
  const int* t = (const int*)d_in[1];
  float* out = (float*)d_out;
  double* partial = (double*)d_ws;

  long long n = (long long)in_sizes[0];
  const double LN2 = 0.69314718055994530942;

  if (n == NELEM) {
    bce_fast_kernel<<<BLOCKS, THREADS, 0, stream>>>(p, t, partial);
    bce_final_kernel<<<1, 256, 0, stream>>>(partial, BLOCKS, out, LN2 / (double)n);
  } else {
    long long nvec = n / 4;
    long long want = (nvec + THREADS - 1) / THREADS;
    int blocks = (int)(want < BLOCKS ? (want > 0 ? want : 1) : BLOCKS);
    bce_generic_kernel<<<blocks, THREADS, 0, stream>>>(p, t, partial, nvec, n);
    bce_final_kernel<<<1, 256, 0, stream>>>(partial, blocks, out, LN2 / (double)n);
  }
}